// Round 1
// baseline (82.372 us; speedup 1.0000x reference)
//
#include <hip/hip_runtime.h>

#define D 32
#define H 128
#define B 32

// tanh(x) = 1 - 2/(exp(2x)+1); v_exp_f32 + v_rcp_f32, ~1 ulp-ish, saturates correctly at +-inf
__device__ __forceinline__ float fast_tanh(float x) {
    float e = __expf(2.0f * x);
    return 1.0f - 2.0f * __builtin_amdgcn_rcpf(e + 1.0f);
}

// ---------------- Stage A: metric + per-batch MLP bases ----------------
// grid = 32 (one block per batch element), block = 256
__global__ __launch_bounds__(256) void setup_kernel(
    const float* __restrict__ points,
    const float* __restrict__ mw1, const float* __restrict__ mb1,
    const float* __restrict__ mw2, const float* __restrict__ mb2,
    const float* __restrict__ cw1, const float* __restrict__ cb1,
    const float* __restrict__ rw1, const float* __restrict__ rb1,
    float* __restrict__ metric, float* __restrict__ cbase, float* __restrict__ rbase)
{
    __shared__ float p[D];
    __shared__ float h1[H];
    const int b = blockIdx.x;
    const int t = threadIdx.x;
    if (t < D) p[t] = points[b * D + t];
    __syncthreads();

    if (t < H) {
        // metric hidden layer
        float acc = mb1[t];
        #pragma unroll
        for (int d = 0; d < D; ++d) acc = fmaf(p[d], mw1[d * H + t], acc);
        h1[t] = fmaxf(acc, 0.0f);
        // christoffel base: points part of cw1 (rows 0..31) + cb1
        float cacc = cb1[t];
        #pragma unroll
        for (int d = 0; d < D; ++d) cacc = fmaf(p[d], cw1[d * H + t], cacc);
        cbase[b * H + t] = cacc;
    }
    // ricci base: points part of rw1 (rows 0..31) + rb1 ; 2H = 256 = blockDim
    {
        float racc = rb1[t];
        #pragma unroll
        for (int d = 0; d < D; ++d) racc = fmaf(p[d], rw1[d * 256 + t], racc);
        rbase[b * 256 + t] = racc;
    }
    __syncthreads();

    // metric output layer: 1024 outputs, 4 per thread
    #pragma unroll
    for (int q = 0; q < 4; ++q) {
        const int m = q * 256 + t;
        float acc = mb2[m];
        for (int h = 0; h < H; ++h) acc = fmaf(h1[h], mw2[h * 1024 + m], acc);
        metric[b * 1024 + m] = acc;
    }
}

// ---------------- Stage B: christoffel, 1M rows ----------------
// Each thread owns 8 consecutive k (same b,i,j): gij scalar, gjk[8], gki[8].
// Per hidden h: 5 broadcast LDS reads + per row {3 FMA, tanh, 1 FMA}.
// grid = 32 batches * 16 = 512 blocks, block = 256
__global__ __launch_bounds__(256) void christoffel_kernel(
    const float* __restrict__ metric, const float* __restrict__ cbase,
    const float* __restrict__ cw1, const float* __restrict__ cw2,
    const float* __restrict__ cb2,
    float* __restrict__ gamma)
{
    __shared__ float M[D * D];                  // metric[b], 4 KB
    __shared__ float base[H], w1[H], w2[H], w3[H], wout[H];
    const int blk = blockIdx.x;
    const int b   = blk >> 4;
    const int sub = blk & 15;
    const int t   = threadIdx.x;

    #pragma unroll
    for (int q = 0; q < 4; ++q) M[q * 256 + t] = metric[b * 1024 + q * 256 + t];
    if (t < H) {
        base[t] = cbase[b * H + t];
        w1[t]   = cw1[32 * H + t];   // g_ij weight
        w2[t]   = cw1[33 * H + t];   // g_jk weight
        w3[t]   = cw1[34 * H + t];   // g_ki weight
        wout[t] = cw2[t];
    }
    __syncthreads();

    const int row = sub * 2048 + t * 8;         // 0..32767 within batch, step 8
    const int i  = row >> 10;
    const int j  = (row >> 5) & 31;
    const int k0 = row & 31;                    // multiple of 8

    const float gij = M[i * 32 + j];
    float gjk[8], gki[8], acc[8];
    #pragma unroll
    for (int r = 0; r < 8; ++r) {
        gjk[r] = M[j * 32 + k0 + r];
        gki[r] = M[(k0 + r) * 32 + i];
        acc[r] = 0.0f;
    }

    #pragma unroll 4
    for (int h = 0; h < H; ++h) {
        const float bb = base[h], a1 = w1[h], a2 = w2[h], a3 = w3[h], ao = wout[h];
        const float pre = fmaf(gij, a1, bb);
        #pragma unroll
        for (int r = 0; r < 8; ++r) {
            const float x = fmaf(gki[r], a3, fmaf(gjk[r], a2, pre));
            acc[r] = fmaf(fast_tanh(x), ao, acc[r]);
        }
    }

    const float c2 = *cb2;
    float* dst = gamma + b * 32768 + row;
    #pragma unroll
    for (int r = 0; r < 8; ++r) dst[r] = acc[r] + c2;
}

// ---------------- Stage C: ricci, 32768 rows ----------------
// Block = (b,i) pair; thread = hidden unit h (256). All 33 weights for this h
// held in registers; per-j gamma row + g_ij are wave-uniform -> scalar loads.
// grid = 1024, block = 256
__global__ __launch_bounds__(256) void ricci_kernel(
    const float* __restrict__ metric, const float* __restrict__ rbase,
    const float* __restrict__ rw1, const float* __restrict__ rw2,
    const float* __restrict__ rb2,
    const float* __restrict__ gamma,
    float* __restrict__ out)
{
    const int b = blockIdx.x >> 5;
    const int i = blockIdx.x & 31;
    const int h = threadIdx.x;

    float w[33];
    #pragma unroll
    for (int f = 0; f < 33; ++f) w[f] = rw1[(32 + f) * 256 + h];
    const float rb = rbase[b * 256 + h];
    const float wo = rw2[h];
    const float rbias = *rb2;

    __shared__ float red[4];
    const float* Mrow = metric + b * 1024 + i * 32;
    const float* G    = gamma + (b * 32 + i) * 1024;

    for (int j = 0; j < 32; ++j) {
        const float gij = Mrow[j];              // wave-uniform
        const float* g = G + j * 32;            // wave-uniform
        float hid = fmaf(gij, w[0], rb);
        #pragma unroll
        for (int k = 0; k < 32; ++k) hid = fmaf(g[k], w[k + 1], hid);
        float part = fmaxf(hid, 0.0f) * wo;
        #pragma unroll
        for (int off = 32; off > 0; off >>= 1) part += __shfl_down(part, off);
        if ((h & 63) == 0) red[h >> 6] = part;
        __syncthreads();
        if (h == 0) out[(b * 32 + i) * 32 + j] = red[0] + red[1] + red[2] + red[3] + rbias;
        __syncthreads();
    }
}

extern "C" void kernel_launch(void* const* d_in, const int* in_sizes, int n_in,
                              void* d_out, int out_size, void* d_ws, size_t ws_size,
                              hipStream_t stream) {
    const float* points = (const float*)d_in[0];
    const float* mw1 = (const float*)d_in[1];
    const float* mb1 = (const float*)d_in[2];
    const float* mw2 = (const float*)d_in[3];
    const float* mb2 = (const float*)d_in[4];
    const float* cw1 = (const float*)d_in[5];
    const float* cb1 = (const float*)d_in[6];
    const float* cw2 = (const float*)d_in[7];
    const float* cb2 = (const float*)d_in[8];
    const float* rw1 = (const float*)d_in[9];
    const float* rb1 = (const float*)d_in[10];
    const float* rw2 = (const float*)d_in[11];
    const float* rb2 = (const float*)d_in[12];
    float* out = (float*)d_out;

    char* ws = (char*)d_ws;
    float* metric = (float*)(ws);                              // 32*1024 f32 = 128 KB
    float* cbase  = (float*)(ws + 131072);                     // 32*128  f32 = 16 KB
    float* rbase  = (float*)(ws + 131072 + 16384);             // 32*256  f32 = 32 KB
    float* gamma  = (float*)(ws + 131072 + 16384 + 32768);     // 32*32768 f32 = 4 MB

    setup_kernel<<<32, 256, 0, stream>>>(points, mw1, mb1, mw2, mb2,
                                         cw1, cb1, rw1, rb1,
                                         metric, cbase, rbase);
    christoffel_kernel<<<512, 256, 0, stream>>>(metric, cbase, cw1, cw2, cb2, gamma);
    ricci_kernel<<<1024, 256, 0, stream>>>(metric, rbase, rw1, rw2, rb2, gamma, out);
}

// Round 2
// 65.393 us; speedup vs baseline: 1.2597x; 1.2597x over previous
//
#include <hip/hip_runtime.h>

#define D 32
#define H 128
#define B 32

// ---------------- Stage A: metric + per-batch MLP bases + folded constants ----------------
// grid = 32 (one block per batch element), block = 256
__global__ __launch_bounds__(256) void setup_kernel(
    const float* __restrict__ points,
    const float* __restrict__ mw1, const float* __restrict__ mb1,
    const float* __restrict__ mw2, const float* __restrict__ mb2,
    const float* __restrict__ cw1, const float* __restrict__ cb1,
    const float* __restrict__ cw2,
    const float* __restrict__ rw1, const float* __restrict__ rb1,
    float* __restrict__ metric, float* __restrict__ cbase, float* __restrict__ rbase,
    float* __restrict__ sumw)
{
    __shared__ float p[D];
    __shared__ float h1[H];
    const int b = blockIdx.x;
    const int t = threadIdx.x;
    if (t < D) p[t] = points[b * D + t];
    __syncthreads();

    if (t < H) {
        // metric hidden layer
        float acc = mb1[t];
        #pragma unroll
        for (int d = 0; d < D; ++d) acc = fmaf(p[d], mw1[d * H + t], acc);
        h1[t] = fmaxf(acc, 0.0f);
        // christoffel base: points part of cw1 (rows 0..31) + cb1
        float cacc = cb1[t];
        #pragma unroll
        for (int d = 0; d < D; ++d) cacc = fmaf(p[d], cw1[d * H + t], cacc);
        cbase[b * H + t] = cacc;
    }
    // ricci base: points part of rw1 (rows 0..31) + rb1 ; 2H = 256 = blockDim
    {
        float racc = rb1[t];
        #pragma unroll
        for (int d = 0; d < D; ++d) racc = fmaf(p[d], rw1[d * 256 + t], racc);
        rbase[b * 256 + t] = racc;
    }
    // sum of cw2 (once, block 0, wave 0)
    if (b == 0 && t < 64) {
        float v = cw2[t] + cw2[t + 64];
        #pragma unroll
        for (int off = 32; off > 0; off >>= 1) v += __shfl_xor(v, off);
        if (t == 0) sumw[0] = v;
    }
    __syncthreads();

    // metric output layer: 1024 outputs, 4 per thread
    #pragma unroll
    for (int q = 0; q < 4; ++q) {
        const int m = q * 256 + t;
        float acc = mb2[m];
        for (int h = 0; h < H; ++h) acc = fmaf(h1[h], mw2[h * 1024 + m], acc);
        metric[b * 1024 + m] = acc;
    }
}

// ---------------- Stage B: christoffel, 1M rows ----------------
// tanh(x) = 1 - 2*rcp(exp2(K*x)+1), K = 2*log2(e) folded into weights/bias.
// Sum_h cw2[h]*tanh = sum(cw2) + Sum_h (-2*cw2[h])*rcp_h  -> 4 VALU + 2 trans per eval.
// 4 rows per thread; grid = 32*32 = 1024 blocks (4 blocks/CU -> 4 waves/SIMD).
__global__ __launch_bounds__(256) void christoffel_kernel(
    const float* __restrict__ metric, const float* __restrict__ cbase,
    const float* __restrict__ cw1, const float* __restrict__ cw2,
    const float* __restrict__ cb2, const float* __restrict__ sumw,
    float* __restrict__ gamma)
{
    __shared__ float M[D * D];          // metric[b], 4 KB
    __shared__ float4 pack[H];          // {K*cbase, K*a1, K*a2, K*a3} per h -> one ds_read_b128
    __shared__ float wm2[H];            // -2*cw2
    const int blk = blockIdx.x;
    const int b   = blk >> 5;
    const int sub = blk & 31;           // == i (block-uniform)
    const int t   = threadIdx.x;

    #pragma unroll
    for (int q = 0; q < 4; ++q) M[q * 256 + t] = metric[b * 1024 + q * 256 + t];
    if (t < H) {
        constexpr float Kc = 2.8853900817779268f;   // 2*log2(e)
        pack[t] = make_float4(Kc * cbase[b * H + t],
                              Kc * cw1[32 * H + t],
                              Kc * cw1[33 * H + t],
                              Kc * cw1[34 * H + t]);
        wm2[t] = -2.0f * cw2[t];
    }
    __syncthreads();

    const int i  = sub;
    const int j  = t >> 3;
    const int k0 = (t & 7) * 4;

    const float gij = M[i * 32 + j];
    float gjk[4], gki[4], acc[4];
    #pragma unroll
    for (int r = 0; r < 4; ++r) {
        gjk[r] = M[j * 32 + k0 + r];
        gki[r] = M[(k0 + r) * 32 + i];
        acc[r] = 0.0f;
    }

    #pragma unroll 8
    for (int h = 0; h < H; ++h) {
        const float4 c = pack[h];
        const float wo = wm2[h];
        const float pre = fmaf(gij, c.y, c.x);
        #pragma unroll
        for (int r = 0; r < 4; ++r) {
            const float x  = fmaf(gki[r], c.w, fmaf(gjk[r], c.z, pre));
            const float e  = __builtin_amdgcn_exp2f(x);
            const float rc = __builtin_amdgcn_rcpf(e + 1.0f);
            acc[r] = fmaf(rc, wo, acc[r]);
        }
    }

    const float addc = sumw[0] + cb2[0];
    float4 res = make_float4(acc[0] + addc, acc[1] + addc, acc[2] + addc, acc[3] + addc);
    *((float4*)(gamma + b * 32768 + sub * 1024 + t * 4)) = res;
}

// ---------------- Stage C: ricci, 32768 rows ----------------
// Block = (b,i); thread = hidden unit h (256). 33 weights in registers (zero reloads).
// Gamma block (4 KB) + metric row staged in LDS; all 32 j without inner barriers.
// grid = 1024, block = 256
__global__ __launch_bounds__(256) void ricci_kernel(
    const float* __restrict__ metric, const float* __restrict__ rbase,
    const float* __restrict__ rw1, const float* __restrict__ rw2,
    const float* __restrict__ rb2,
    const float* __restrict__ gamma,
    float* __restrict__ out)
{
    __shared__ float Gs[1024];
    __shared__ float Ms[32];
    __shared__ float red[4][32];
    const int bi = blockIdx.x;
    const int b  = bi >> 5;
    const int i  = bi & 31;
    const int t  = threadIdx.x;

    float w[33];
    #pragma unroll
    for (int f = 0; f < 33; ++f) w[f] = rw1[(32 + f) * 256 + t];
    const float rb    = rbase[b * 256 + t];
    const float wo    = rw2[t];
    const float rbias = rb2[0];

    ((float4*)Gs)[t] = ((const float4*)(gamma + bi * 1024))[t];
    if (t < 32) Ms[t] = metric[b * 1024 + i * 32 + t];
    __syncthreads();

    const int wid  = t >> 6;
    const int lane = t & 63;

    for (int j = 0; j < 32; ++j) {
        float hid = fmaf(Ms[j], w[0], rb);
        #pragma unroll
        for (int k4 = 0; k4 < 8; ++k4) {
            const float4 g = ((float4*)Gs)[j * 8 + k4];
            hid = fmaf(g.x, w[k4 * 4 + 1], hid);
            hid = fmaf(g.y, w[k4 * 4 + 2], hid);
            hid = fmaf(g.z, w[k4 * 4 + 3], hid);
            hid = fmaf(g.w, w[k4 * 4 + 4], hid);
        }
        float p = fmaxf(hid, 0.0f) * wo;
        #pragma unroll
        for (int off = 32; off > 0; off >>= 1) p += __shfl_xor(p, off);
        if (lane == 0) red[wid][j] = p;
    }
    __syncthreads();
    if (t < 32) out[bi * 32 + t] = red[0][t] + red[1][t] + red[2][t] + red[3][t] + rbias;
}

extern "C" void kernel_launch(void* const* d_in, const int* in_sizes, int n_in,
                              void* d_out, int out_size, void* d_ws, size_t ws_size,
                              hipStream_t stream) {
    const float* points = (const float*)d_in[0];
    const float* mw1 = (const float*)d_in[1];
    const float* mb1 = (const float*)d_in[2];
    const float* mw2 = (const float*)d_in[3];
    const float* mb2 = (const float*)d_in[4];
    const float* cw1 = (const float*)d_in[5];
    const float* cb1 = (const float*)d_in[6];
    const float* cw2 = (const float*)d_in[7];
    const float* cb2 = (const float*)d_in[8];
    const float* rw1 = (const float*)d_in[9];
    const float* rb1 = (const float*)d_in[10];
    const float* rw2 = (const float*)d_in[11];
    const float* rb2 = (const float*)d_in[12];
    float* out = (float*)d_out;

    char* ws = (char*)d_ws;
    float* metric = (float*)(ws);                      // 32*1024 f32 = 128 KB
    float* cbase  = (float*)(ws + 131072);             // 32*128  f32 = 16 KB
    float* rbase  = (float*)(ws + 147456);             // 32*256  f32 = 32 KB
    float* sumw   = (float*)(ws + 180224);             // 1 f32 (+pad)
    float* gamma  = (float*)(ws + 180480);             // 32*32768 f32 = 4 MB

    setup_kernel<<<32, 256, 0, stream>>>(points, mw1, mb1, mw2, mb2,
                                         cw1, cb1, cw2, rw1, rb1,
                                         metric, cbase, rbase, sumw);
    christoffel_kernel<<<1024, 256, 0, stream>>>(metric, cbase, cw1, cw2, cb2, sumw, gamma);
    ricci_kernel<<<1024, 256, 0, stream>>>(metric, rbase, rw1, rw2, rb2, gamma, out);
}